// Round 3
// baseline (74.869 us; speedup 1.0000x reference)
//
#include <hip/hip_runtime.h>

// AllZeroDigitalFilter: time-varying FIR with linearly-interpolated coefficients.
//   out[b,t] = sum_{k=0..255} x[b,t-k] * ((1-f)*h[b,n,k] + f*h[b,n1,k])
//   n = t/80, f = (t%80)/80, n1 = min(n+1, N-1), x[neg] = 0
// B=8, N=800, P=80, T=64000, TAPS=256.
//
// v3: split-K x4 for occupancy. R2 analysis: 2000 waves (~2/SIMD) left the
// kernel ds_read-latency bound at ~28 us. Now 1600 blocks x 5 waves = 31
// waves/CU; each block does 64 taps, writes blended partials to d_ws; a
// float4 reduce kernel sums the 4 partials (blend is linear in the k-sum).

#define TAPS 256
#define PP 80
#define BB 8
#define NN 800
#define TT (NN * PP)
#define SPLITS 4
#define KSPL (TAPS / SPLITS)      // 64 taps per split
#define FPB 16                    // frames per block
#define TPF 20                    // threads per frame
#define RR 4                      // outputs per thread
#define NTHREADS (FPB * TPF)      // 320
#define HSTRIDE 68                // floats: 64 taps + 4 zero tail; 272 B (16B-aligned, +4 bank shift/row)
#define XB 68                     // sx index of x[t0 - ks]; 272 B (16B-aligned)
#define XLEN (FPB * PP + XB + 4)  // 1352 floats
#define CHUNKS (NN / FPB)         // 50

__global__ __launch_bounds__(NTHREADS) void azdf_split_kernel(
    const float* __restrict__ x, const float* __restrict__ h,
    float* __restrict__ ws)
{
    __shared__ float sh[(FPB + 1) * HSTRIDE];   // 17*68*4 = 4624 B
    __shared__ float sx[XLEN];                  // 5408 B

    const int tid   = threadIdx.x;
    const int blk   = blockIdx.x;
    const int split = blockIdx.y;
    const int ks    = split * KSPL;
    const int b     = blk / CHUNKS;
    const int nc    = blk % CHUNKS;
    const int n0    = nc * FPB;
    const int t0    = n0 * PP;

    // ---- stage h rows n0 .. n0+FPB (clamped), taps ks..ks+63, float4 ----
    const float* hb = h + (size_t)b * NN * TAPS + ks;
    for (int i = tid; i < (FPB + 1) * (KSPL / 4); i += NTHREADS) {
        int r  = i >> 4;           // row 0..16
        int q  = i & 15;           // float4 index in row
        int gr = n0 + r;
        if (gr > NN - 1) gr = NN - 1;
        float4 v = ((const float4*)(hb + (size_t)gr * TAPS))[q];
        ((float4*)(sh + r * HSTRIDE))[q] = v;
    }
    // zero tail float4 of each row (read by the in-loop prefetch, never used)
    for (int r = tid; r < FPB + 1; r += NTHREADS) {
        ((float4*)(sh + r * HSTRIDE))[KSPL / 4] = make_float4(0.f, 0.f, 0.f, 0.f);
    }

    // ---- stage x: sx[i] = x[t0 - ks - XB + i], zero-padded ----
    const float* xb = x + (size_t)b * TT;
    for (int i = tid; i < XLEN; i += NTHREADS) {
        int g = t0 - ks - XB + i;
        sx[i] = (g >= 0 && g < TT) ? xb[g] : 0.0f;
    }
    __syncthreads();

    // ---- compute: thread -> 4 consecutive outputs t = t0 + 4*tid + r,
    //      taps kk = 0..63 within this split (absolute k = ks + kk) ----
    const int lf    = tid / TPF;            // local frame 0..15
    const int p0    = (tid % TPF) * RR;     // phase of output r=0
    const int xbase = XB + 4 * tid;         // sx index of x[t0 + 4*tid - ks]
    const float* hA = sh + lf * HSTRIDE;
    const float* hB = hA + HSTRIDE;

    float acc0[RR], acc1[RR];
    #pragma unroll
    for (int r = 0; r < RR; ++r) { acc0[r] = 0.0f; acc1[r] = 0.0f; }

    // register window W[j] = sx[xbase - kk - 4 + j], j=0..7
    float W[8];
    *(float4*)&W[0] = *(const float4*)&sx[xbase - 4];
    *(float4*)&W[4] = *(const float4*)&sx[xbase];

    float4 c0 = *(const float4*)hA;
    float4 c1 = *(const float4*)hB;

    #pragma unroll 4
    for (int kk = 0; kk < KSPL; kk += 4) {
        float4 u0 = c0, u1 = c1;
        // prefetch next iteration's operands (tails are staged zeros / in-bounds)
        c0 = *(const float4*)(hA + kk + 4);
        c1 = *(const float4*)(hB + kk + 4);
        float4 xn = *(const float4*)&sx[xbase - kk - 8];

        const float* u0f = (const float*)&u0;
        const float* u1f = (const float*)&u1;
        #pragma unroll
        for (int d = 0; d < 4; ++d) {
            float cc0 = u0f[d];
            float cc1 = u1f[d];
            #pragma unroll
            for (int r = 0; r < RR; ++r) {
                float xr = W[r - d + 4];    // sx[xbase + r - (kk+d)]
                acc0[r] = fmaf(xr, cc0, acc0[r]);
                acc1[r] = fmaf(xr, cc1, acc1[r]);
            }
        }
        // slide window down by 4
        W[4] = W[0]; W[5] = W[1]; W[6] = W[2]; W[7] = W[3];
        *(float4*)&W[0] = xn;
    }

    // ---- epilogue: blend (linear in partial sums) and store partial float4 ----
    float4 o;
    float* of = (float*)&o;
    #pragma unroll
    for (int r = 0; r < RR; ++r) {
        float f = (float)(p0 + r) * (1.0f / PP);
        of[r] = acc0[r] + f * (acc1[r] - acc0[r]);
    }
    *(float4*)(ws + (size_t)split * BB * TT + (size_t)b * TT + t0 + 4 * tid) = o;
}

__global__ __launch_bounds__(256) void azdf_reduce_kernel(
    const float* __restrict__ ws, float* __restrict__ out)
{
    int i = (blockIdx.x * 256 + threadIdx.x);   // float4 index
    const float4* p0 = (const float4*)ws;
    const float4* p1 = (const float4*)(ws + (size_t)1 * BB * TT);
    const float4* p2 = (const float4*)(ws + (size_t)2 * BB * TT);
    const float4* p3 = (const float4*)(ws + (size_t)3 * BB * TT);
    float4 a = p0[i], b = p1[i], c = p2[i], d = p3[i];
    float4 o;
    o.x = (a.x + b.x) + (c.x + d.x);
    o.y = (a.y + b.y) + (c.y + d.y);
    o.z = (a.z + b.z) + (c.z + d.z);
    o.w = (a.w + b.w) + (c.w + d.w);
    ((float4*)out)[i] = o;
}

extern "C" void kernel_launch(void* const* d_in, const int* in_sizes, int n_in,
                              void* d_out, int out_size, void* d_ws, size_t ws_size,
                              hipStream_t stream) {
    const float* x = (const float*)d_in[0];
    const float* h = (const float*)d_in[1];
    float* out    = (float*)d_out;
    float* ws     = (float*)d_ws;

    dim3 grid(BB * CHUNKS, SPLITS);
    azdf_split_kernel<<<grid, NTHREADS, 0, stream>>>(x, h, ws);

    int n4 = BB * TT / 4;                      // 131072 float4s
    azdf_reduce_kernel<<<n4 / 256, 256, 0, stream>>>(ws, out);
}

// Round 4
// 71.506 us; speedup vs baseline: 1.0470x; 1.0470x over previous
//
#include <hip/hip_runtime.h>

// AllZeroDigitalFilter: time-varying FIR with linearly-interpolated coefficients.
//   out[b,t] = sum_{k=0..255} x[b,t-k] * ((1-f)*h[b,n,k] + f*h[b,n1,k])
//   n = t/80, f = (t%80)/80, n1 = min(n+1, N-1), x[neg] = 0
// B=8, N=800, P=80, T=64000, TAPS=256.
//
// v4: single kernel (split-K reverted: R3 showed it only added launch + ws
// traffic). R2 inner loop (b128 LDS reads + register x shift-window) with:
//   - branch-free float4 x staging for interior blocks (48/50 of blocks)
//   - #pragma unroll 8 tap loop
//   - direct blended float4 store to d_out
// Evidence from R1-R3: reported dur_us is dominated by a ~70 us harness floor
// (268 MB d_ws re-poison fill = 42 us/iter in profile + restores + launch
// gaps); kernel-side deltas are nearly invisible in dur_us.

#define TAPS 256
#define PP 80
#define BB 8
#define NN 800
#define TT (NN * PP)
#define FPB 16                    // frames per block
#define TPF 20                    // threads per frame
#define RR 4                      // outputs per thread
#define NTHREADS (FPB * TPF)      // 320 = 5 waves
#define HSTRIDE 260               // floats; 1040 B row stride: 16B-aligned, +4 bank shift
#define XB 260                    // sx index of x[t0]; multiple of 4
#define XLEN (FPB * PP + XB + 4)  // 1544 floats
#define CHUNKS (NN / FPB)         // 50

__global__ __launch_bounds__(NTHREADS, 6) void azdf_kernel(
    const float* __restrict__ x, const float* __restrict__ h,
    float* __restrict__ out)
{
    __shared__ float sh[(FPB + 1) * HSTRIDE];   // 17680 B
    __shared__ float sx[XLEN];                  // 6176 B

    const int tid = threadIdx.x;
    const int blk = blockIdx.x;
    const int b   = blk / CHUNKS;
    const int nc  = blk % CHUNKS;
    const int n0  = nc * FPB;
    const int t0  = n0 * PP;

    // ---- stage h rows n0 .. n0+FPB (clamped), float4 ----
    const float* hb = h + (size_t)b * NN * TAPS;
    for (int i = tid; i < (FPB + 1) * (TAPS / 4); i += NTHREADS) {
        int r  = i >> 6;           // row 0..16
        int q  = i & 63;           // float4 index in row
        int gr = n0 + r;
        if (gr > NN - 1) gr = NN - 1;
        float4 v = ((const float4*)(hb + (size_t)gr * TAPS))[q];
        ((float4*)(sh + r * HSTRIDE))[q] = v;
    }

    // ---- stage x: sx[i] = x[t0 - XB + i] ----
    const float* xb = x + (size_t)b * TT;
    const int g0 = t0 - XB;                     // multiple of 4
    if (nc != 0 && nc != CHUNKS - 1) {
        // interior: fully in-bounds, branch-free float4 staging
        const float4* src = (const float4*)(xb + g0);
        for (int i = tid; i < XLEN / 4; i += NTHREADS)
            ((float4*)sx)[i] = src[i];
    } else {
        for (int i = tid; i < XLEN; i += NTHREADS) {
            int g = g0 + i;
            sx[i] = (g >= 0 && g < TT) ? xb[g] : 0.0f;
        }
    }
    __syncthreads();

    // ---- compute: thread -> 4 consecutive outputs t = t0 + 4*tid + r ----
    const int lf    = tid / TPF;            // local frame 0..15
    const int p0    = (tid % TPF) * RR;     // phase of output r=0
    const int xbase = XB + 4 * tid;         // sx index of x[t] for r=0 (mult of 4)
    const float* hA = sh + lf * HSTRIDE;
    const float* hB = hA + HSTRIDE;

    float acc0[RR], acc1[RR];
    #pragma unroll
    for (int r = 0; r < RR; ++r) { acc0[r] = 0.0f; acc1[r] = 0.0f; }

    // register window W[j] = sx[xbase - k - 4 + j], j=0..7
    float W[8];
    *(float4*)&W[0] = *(const float4*)&sx[xbase - 4];
    *(float4*)&W[4] = *(const float4*)&sx[xbase];

    float4 c0 = *(const float4*)hA;
    float4 c1 = *(const float4*)hB;

    #pragma unroll 8
    for (int k = 0; k < TAPS; k += 4) {
        float4 u0 = c0, u1 = c1;
        // prefetch next iteration's operands (all reads in-bounds by construction;
        // the final iteration's prefetch reads sh row tail / sx low end, unused)
        c0 = *(const float4*)(hA + k + 4);
        c1 = *(const float4*)(hB + k + 4);
        float4 xn = *(const float4*)&sx[xbase - k - 8];

        const float* u0f = (const float*)&u0;
        const float* u1f = (const float*)&u1;
        #pragma unroll
        for (int d = 0; d < 4; ++d) {
            float cc0 = u0f[d];
            float cc1 = u1f[d];
            #pragma unroll
            for (int r = 0; r < RR; ++r) {
                float xr = W[r - d + 4];    // sx[xbase + r - (k+d)]
                acc0[r] = fmaf(xr, cc0, acc0[r]);
                acc1[r] = fmaf(xr, cc1, acc1[r]);
            }
        }
        // slide window down by 4
        W[4] = W[0]; W[5] = W[1]; W[6] = W[2]; W[7] = W[3];
        *(float4*)&W[0] = xn;
    }

    // NOTE: last-iteration prefetch of c0/c1 reads hA/hB + 256.. which for
    // lf==15 hB row 16 ends at sh[16*260+259] -- still inside sh[] (4420
    // floats). In-bounds, values unused.

    // ---- epilogue: blend and store float4 ----
    float4 o;
    float* of = (float*)&o;
    #pragma unroll
    for (int r = 0; r < RR; ++r) {
        float f = (float)(p0 + r) * (1.0f / PP);
        of[r] = fmaf(f, acc1[r] - acc0[r], acc0[r]);
    }
    *(float4*)(out + (size_t)b * TT + t0 + 4 * tid) = o;
}

extern "C" void kernel_launch(void* const* d_in, const int* in_sizes, int n_in,
                              void* d_out, int out_size, void* d_ws, size_t ws_size,
                              hipStream_t stream) {
    const float* x = (const float*)d_in[0];
    const float* h = (const float*)d_in[1];
    float* out    = (float*)d_out;
    azdf_kernel<<<BB * CHUNKS, NTHREADS, 0, stream>>>(x, h, out);
}